// Round 1
// baseline (1680.320 us; speedup 1.0000x reference)
//
#include <hip/hip_runtime.h>
#include <hip/hip_bf16.h>

#define DFEAT 64

// ---------------- degree count (int atomics) ----------------
__global__ void deg_kernel(const int* __restrict__ uidx,
                           const int* __restrict__ sidx,
                           unsigned int* __restrict__ udeg,
                           unsigned int* __restrict__ sdeg,
                           int n_edges) {
    int e = blockIdx.x * blockDim.x + threadIdx.x;
    if (e < n_edges) {
        atomicAdd(&udeg[uidx[e]], 1u);
        atomicAdd(&sdeg[sidx[e]], 1u);
    }
}

// ---------------- deg -> rsqrt(deg) in place ----------------
__global__ void rsqrt_kernel(unsigned int* __restrict__ deg_as_uint,
                             float* __restrict__ isq, int n) {
    int i = blockIdx.x * blockDim.x + threadIdx.x;
    if (i < n) {
        float d = (float)deg_as_uint[i];
        if (d == 0.0f) d = 1e-6f;
        isq[i] = rsqrtf(d);
    }
}

// ---------------- edge scatter: 64 threads per edge ----------------
__global__ void scatter_kernel(const float* __restrict__ user_x,
                               const float* __restrict__ spot_x,
                               const int* __restrict__ uidx,
                               const int* __restrict__ sidx,
                               const float* __restrict__ isqu,
                               const float* __restrict__ isqs,
                               float* __restrict__ user_out,
                               float* __restrict__ spot_out,
                               int n_edges) {
    long long t = (long long)blockIdx.x * blockDim.x + threadIdx.x;
    int e = (int)(t >> 6);
    int lane = (int)(t & 63);
    if (e < n_edges) {
        int u = uidx[e];
        int s = sidx[e];
        float su = isqu[u];
        float ss = isqs[s];
        // message spot->user, pre-normalized by spot degree
        float sv = spot_x[(long long)s * DFEAT + lane] * ss;
        // message user->spot, pre-normalized by user degree
        float uv = user_x[(long long)u * DFEAT + lane] * su;
        unsafeAtomicAdd(&user_out[(long long)u * DFEAT + lane], sv);
        unsafeAtomicAdd(&spot_out[(long long)s * DFEAT + lane], uv);
    }
}

// ---------------- post-normalize by destination degree ----------------
__global__ void scale_kernel(float* __restrict__ user_out,
                             float* __restrict__ spot_out,
                             const float* __restrict__ isqu,
                             const float* __restrict__ isqs,
                             int n_users, int n_spots) {
    long long t = (long long)blockIdx.x * blockDim.x + threadIdx.x;
    long long total_u = (long long)n_users * DFEAT;
    long long total_s = (long long)n_spots * DFEAT;
    if (t < total_u) {
        user_out[t] *= isqu[t >> 6];
    } else if (t < total_u + total_s) {
        long long t2 = t - total_u;
        spot_out[t2] *= isqs[t2 >> 6];
    }
}

extern "C" void kernel_launch(void* const* d_in, const int* in_sizes, int n_in,
                              void* d_out, int out_size, void* d_ws, size_t ws_size,
                              hipStream_t stream) {
    const float* user_x = (const float*)d_in[0];
    const float* spot_x = (const float*)d_in[1];
    const int* uidx = (const int*)d_in[2];
    const int* sidx = (const int*)d_in[3];

    const int n_users = in_sizes[0] / DFEAT;   // 200000
    const int n_spots = in_sizes[1] / DFEAT;   // 50000
    const int n_edges = in_sizes[2];           // 3200000

    float* user_out = (float*)d_out;
    float* spot_out = (float*)d_out + (long long)n_users * DFEAT;

    // workspace layout: [0, n_users) = user deg/isq, [n_users, n_users+n_spots) = spot deg/isq
    float* isqu = (float*)d_ws;
    float* isqs = isqu + n_users;
    unsigned int* udeg = (unsigned int*)isqu;
    unsigned int* sdeg = (unsigned int*)isqs;

    // zero outputs (poisoned 0xAA before every timed launch) and degree arrays
    hipMemsetAsync(d_out, 0, (size_t)out_size * sizeof(float), stream);
    hipMemsetAsync(d_ws, 0, (size_t)(n_users + n_spots) * sizeof(unsigned int), stream);

    // 1. degrees
    {
        int threads = 256;
        int blocks = (n_edges + threads - 1) / threads;
        deg_kernel<<<blocks, threads, 0, stream>>>(uidx, sidx, udeg, sdeg, n_edges);
    }
    // 2. rsqrt in place
    {
        int threads = 256;
        int n = n_users + n_spots;
        int blocks = (n + threads - 1) / threads;
        rsqrt_kernel<<<blocks, threads, 0, stream>>>((unsigned int*)d_ws, (float*)d_ws, n);
    }
    // 3. scatter (64 threads per edge)
    {
        int threads = 256;
        long long total = (long long)n_edges * DFEAT;
        long long blocks = (total + threads - 1) / threads;
        scatter_kernel<<<(int)blocks, threads, 0, stream>>>(
            user_x, spot_x, uidx, sidx, isqu, isqs, user_out, spot_out, n_edges);
    }
    // 4. post-scale
    {
        int threads = 256;
        long long total = (long long)(n_users + n_spots) * DFEAT;
        long long blocks = (total + threads - 1) / threads;
        scale_kernel<<<(int)blocks, threads, 0, stream>>>(
            user_out, spot_out, isqu, isqs, n_users, n_spots);
    }
}

// Round 2
// 1363.433 us; speedup vs baseline: 1.2324x; 1.2324x over previous
//
#include <hip/hip_runtime.h>
#include <hip/hip_bf16.h>

#define DFEAT 64
#define SCAN_TPB 256
#define SCAN_EPB 1024   // 4 elements per thread

// ======================= CSR path =======================

// ---------------- degree count (int atomics) ----------------
__global__ void deg_kernel2(const int* __restrict__ uidx,
                            const int* __restrict__ sidx,
                            unsigned int* __restrict__ deg, // [n_users + n_spots]
                            int n_edges, int n_users) {
    int e = blockIdx.x * blockDim.x + threadIdx.x;
    if (e < n_edges) {
        atomicAdd(&deg[uidx[e]], 1u);
        atomicAdd(&deg[n_users + sidx[e]], 1u);
    }
}

// ---------------- scan phase 1: per-block exclusive scan + block sums ----------------
__global__ void scan_phase1(const unsigned int* __restrict__ deg,
                            int* __restrict__ start,
                            unsigned int* __restrict__ bsums, int A) {
    __shared__ unsigned int lds[SCAN_TPB];
    int t = threadIdx.x, b = blockIdx.x;
    int base = b * SCAN_EPB + t * 4;
    unsigned int v[4];
    unsigned int s = 0;
#pragma unroll
    for (int k = 0; k < 4; k++) {
        int i = base + k;
        v[k] = (i < A) ? deg[i] : 0u;
        s += v[k];
    }
    lds[t] = s;
    __syncthreads();
    for (int off = 1; off < SCAN_TPB; off <<= 1) {
        unsigned int x = (t >= off) ? lds[t - off] : 0u;
        __syncthreads();
        lds[t] += x;
        __syncthreads();
    }
    unsigned int excl = lds[t] - s;
    if (t == SCAN_TPB - 1) bsums[b] = lds[t];
    unsigned int run = excl;
#pragma unroll
    for (int k = 0; k < 4; k++) {
        int i = base + k;
        if (i < A) start[i] = (int)run;
        run += v[k];
    }
}

// ---------------- scan phase 2: exclusive scan of block sums (nb <= 256) ----------------
__global__ void scan_phase2(unsigned int* __restrict__ bsums, int nb) {
    __shared__ unsigned int lds[SCAN_TPB];
    int t = threadIdx.x;
    unsigned int v = (t < nb) ? bsums[t] : 0u;
    lds[t] = v;
    __syncthreads();
    for (int off = 1; off < SCAN_TPB; off <<= 1) {
        unsigned int x = (t >= off) ? lds[t - off] : 0u;
        __syncthreads();
        lds[t] += x;
        __syncthreads();
    }
    if (t < nb) bsums[t] = lds[t] - v;   // exclusive
}

// ---------------- finalize: add block offsets, init cursors, deg -> rsqrt ----------------
__global__ void finalize_kernel(unsigned int* __restrict__ deg_isq, // becomes float isq
                                int* __restrict__ start,
                                int* __restrict__ cur,
                                const unsigned int* __restrict__ bsums, int A) {
    int i = blockIdx.x * blockDim.x + threadIdx.x;
    if (i < A) {
        int s = start[i] + (int)bsums[i >> 10];  // SCAN_EPB = 1024
        start[i] = s;
        cur[i] = s;
        unsigned int d = deg_isq[i];
        float df = d ? (float)d : 1e-6f;
        ((float*)deg_isq)[i] = rsqrtf(df);
    }
}

// ---------------- fill edge lists ----------------
__global__ void fill_kernel(const int* __restrict__ uidx,
                            const int* __restrict__ sidx,
                            int* __restrict__ cur,
                            int* __restrict__ u_edges,   // spot index per edge, bucketed by user
                            int* __restrict__ s_edges,   // user index per edge, bucketed by spot
                            int n_edges, int n_users) {
    int e = blockIdx.x * blockDim.x + threadIdx.x;
    if (e < n_edges) {
        int u = uidx[e];
        int s = sidx[e];
        int pu = atomicAdd(&cur[u], 1);
        u_edges[pu] = s;
        int ps = atomicAdd(&cur[n_users + s], 1);
        s_edges[ps - n_edges] = u;   // spot starts are offset by total user degree = n_edges
    }
}

// ---------------- fused gather: one wave per output node, lane = feature ----------------
__global__ __launch_bounds__(256) void gather_kernel(
        const float* __restrict__ user_x,
        const float* __restrict__ spot_x,
        const float* __restrict__ isq,      // [n_users + n_spots]
        const int* __restrict__ start,      // [n_users + n_spots]
        const int* __restrict__ u_edges,
        const int* __restrict__ s_edges,
        float* __restrict__ user_out,
        float* __restrict__ spot_out,
        int n_users, int n_spots, int n_edges) {
    long long t = (long long)blockIdx.x * blockDim.x + threadIdx.x;
    int w = (int)(t >> 6);
    int lane = (int)(t & 63);
    if (w < n_users) {
        int beg = start[w];
        int end = start[w + 1];   // w = n_users-1 -> start[n_users] = n_edges (valid)
        float acc = 0.0f;
        for (int i = beg; i < end; i += 64) {
            int n = end - i; if (n > 64) n = 64;
            int   sv = (lane < n) ? u_edges[i + lane] : 0;
            float fv = (lane < n) ? isq[n_users + sv] : 0.0f;
#pragma unroll 8
            for (int j = 0; j < n; j++) {
                int s   = __shfl(sv, j);
                float f = __shfl(fv, j);
                acc += spot_x[(long long)s * DFEAT + lane] * f;
            }
        }
        user_out[(long long)w * DFEAT + lane] = acc * isq[w];
    } else if (w < n_users + n_spots) {
        int sj = w - n_users;
        int beg = start[w] - n_edges;
        int end = ((sj + 1 < n_spots) ? start[w + 1] : 2 * n_edges) - n_edges;
        float acc = 0.0f;
        for (int i = beg; i < end; i += 64) {
            int n = end - i; if (n > 64) n = 64;
            int   uv = (lane < n) ? s_edges[i + lane] : 0;
            float fv = (lane < n) ? isq[uv] : 0.0f;
#pragma unroll 8
            for (int j = 0; j < n; j++) {
                int u   = __shfl(uv, j);
                float f = __shfl(fv, j);
                acc += user_x[(long long)u * DFEAT + lane] * f;
            }
        }
        spot_out[(long long)sj * DFEAT + lane] = acc * isq[w];
    }
}

// ======================= fallback atomic path (round-1) =======================

__global__ void deg_kernel(const int* __restrict__ uidx,
                           const int* __restrict__ sidx,
                           unsigned int* __restrict__ udeg,
                           unsigned int* __restrict__ sdeg,
                           int n_edges) {
    int e = blockIdx.x * blockDim.x + threadIdx.x;
    if (e < n_edges) {
        atomicAdd(&udeg[uidx[e]], 1u);
        atomicAdd(&sdeg[sidx[e]], 1u);
    }
}

__global__ void rsqrt_kernel(unsigned int* __restrict__ deg_as_uint,
                             float* __restrict__ isq, int n) {
    int i = blockIdx.x * blockDim.x + threadIdx.x;
    if (i < n) {
        float d = (float)deg_as_uint[i];
        if (d == 0.0f) d = 1e-6f;
        isq[i] = rsqrtf(d);
    }
}

__global__ void scatter_kernel(const float* __restrict__ user_x,
                               const float* __restrict__ spot_x,
                               const int* __restrict__ uidx,
                               const int* __restrict__ sidx,
                               const float* __restrict__ isqu,
                               const float* __restrict__ isqs,
                               float* __restrict__ user_out,
                               float* __restrict__ spot_out,
                               int n_edges) {
    long long t = (long long)blockIdx.x * blockDim.x + threadIdx.x;
    int e = (int)(t >> 6);
    int lane = (int)(t & 63);
    if (e < n_edges) {
        int u = uidx[e];
        int s = sidx[e];
        float su = isqu[u];
        float ss = isqs[s];
        float sv = spot_x[(long long)s * DFEAT + lane] * ss;
        float uv = user_x[(long long)u * DFEAT + lane] * su;
        unsafeAtomicAdd(&user_out[(long long)u * DFEAT + lane], sv);
        unsafeAtomicAdd(&spot_out[(long long)s * DFEAT + lane], uv);
    }
}

__global__ void scale_kernel(float* __restrict__ user_out,
                             float* __restrict__ spot_out,
                             const float* __restrict__ isqu,
                             const float* __restrict__ isqs,
                             int n_users, int n_spots) {
    long long t = (long long)blockIdx.x * blockDim.x + threadIdx.x;
    long long total_u = (long long)n_users * DFEAT;
    long long total_s = (long long)n_spots * DFEAT;
    if (t < total_u) {
        user_out[t] *= isqu[t >> 6];
    } else if (t < total_u + total_s) {
        long long t2 = t - total_u;
        spot_out[t2] *= isqs[t2 >> 6];
    }
}

// ======================= launch =======================

extern "C" void kernel_launch(void* const* d_in, const int* in_sizes, int n_in,
                              void* d_out, int out_size, void* d_ws, size_t ws_size,
                              hipStream_t stream) {
    const float* user_x = (const float*)d_in[0];
    const float* spot_x = (const float*)d_in[1];
    const int* uidx = (const int*)d_in[2];
    const int* sidx = (const int*)d_in[3];

    const int n_users = in_sizes[0] / DFEAT;   // 200000
    const int n_spots = in_sizes[1] / DFEAT;   // 50000
    const int n_edges = in_sizes[2];           // 3200000
    const int A = n_users + n_spots;

    float* user_out = (float*)d_out;
    float* spot_out = (float*)d_out + (long long)n_users * DFEAT;

    // CSR workspace layout (4-byte elements):
    //   [0, A)        deg (uint) -> isq (float, in place)
    //   [A, 2A)       start (int, exclusive scan of deg)
    //   [2A, 3A)      cur (int cursors)
    //   [3A, 3A+1024) bsums (scan block sums)
    //   [3A+1024, +E) u_edges
    //   [.., +E)      s_edges
    const long long E_off = 3LL * A + 1024;
    const long long need = (E_off + 2LL * n_edges) * 4;
    const int nblocks_scan = (A + SCAN_EPB - 1) / SCAN_EPB;  // 245 for A=250000

    if ((long long)ws_size >= need && nblocks_scan <= SCAN_TPB) {
        unsigned int* deg_isq = (unsigned int*)d_ws;
        int* start = (int*)d_ws + A;
        int* cur = (int*)d_ws + 2LL * A;
        unsigned int* bsums = (unsigned int*)d_ws + 3LL * A;
        int* u_edges = (int*)d_ws + E_off;
        int* s_edges = u_edges + n_edges;

        hipMemsetAsync(d_ws, 0, (size_t)A * 4, stream);

        {   // degrees
            int threads = 256;
            int blocks = (n_edges + threads - 1) / threads;
            deg_kernel2<<<blocks, threads, 0, stream>>>(uidx, sidx, deg_isq, n_edges, n_users);
        }
        scan_phase1<<<nblocks_scan, SCAN_TPB, 0, stream>>>(deg_isq, start, bsums, A);
        scan_phase2<<<1, SCAN_TPB, 0, stream>>>(bsums, nblocks_scan);
        {
            int threads = 256;
            int blocks = (A + threads - 1) / threads;
            finalize_kernel<<<blocks, threads, 0, stream>>>(deg_isq, start, cur, bsums, A);
        }
        {
            int threads = 256;
            int blocks = (n_edges + threads - 1) / threads;
            fill_kernel<<<blocks, threads, 0, stream>>>(uidx, sidx, cur, u_edges, s_edges,
                                                        n_edges, n_users);
        }
        {
            int threads = 256;
            long long total = (long long)A * 64;
            int blocks = (int)((total + threads - 1) / threads);
            gather_kernel<<<blocks, threads, 0, stream>>>(
                user_x, spot_x, (const float*)deg_isq, start, u_edges, s_edges,
                user_out, spot_out, n_users, n_spots, n_edges);
        }
    } else {
        // fallback: atomic scatter path
        float* isqu = (float*)d_ws;
        float* isqs = isqu + n_users;
        unsigned int* udeg = (unsigned int*)isqu;
        unsigned int* sdeg = (unsigned int*)isqs;

        hipMemsetAsync(d_out, 0, (size_t)out_size * sizeof(float), stream);
        hipMemsetAsync(d_ws, 0, (size_t)A * sizeof(unsigned int), stream);

        {
            int threads = 256;
            int blocks = (n_edges + threads - 1) / threads;
            deg_kernel<<<blocks, threads, 0, stream>>>(uidx, sidx, udeg, sdeg, n_edges);
        }
        {
            int threads = 256;
            int blocks = (A + threads - 1) / threads;
            rsqrt_kernel<<<blocks, threads, 0, stream>>>((unsigned int*)d_ws, (float*)d_ws, A);
        }
        {
            int threads = 256;
            long long total = (long long)n_edges * 64;
            int blocks = (int)((total + threads - 1) / threads);
            scatter_kernel<<<blocks, threads, 0, stream>>>(
                user_x, spot_x, uidx, sidx, isqu, isqs, user_out, spot_out, n_edges);
        }
        {
            int threads = 256;
            long long total = (long long)A * 64;
            int blocks = (int)((total + threads - 1) / threads);
            scale_kernel<<<blocks, threads, 0, stream>>>(
                user_out, spot_out, isqu, isqs, n_users, n_spots);
        }
    }
}